// Round 8
// baseline (1004.932 us; speedup 1.0000x reference)
//
#include <hip/hip_runtime.h>

// Problem constants
constexpr int Bn    = 4;
constexpr int Hn    = 192;
constexpr int Wn    = 192;
constexpr int Cn    = 16;
constexpr int HIDn  = 128;
constexpr int HWn   = Hn * Wn;        // 36864
constexpr int BHWn  = Bn * HWn;       // 147456
constexpr int STEPSn = 10;
constexpr int PADn  = 4;
constexpr int KSn   = 9;
constexpr float EPSf  = 1e-5f;
constexpr float FIREf = 0.5f;

// conv kernel geometry: 64 cols x 2 rows per block, 4 waves (channel quads)
constexpr int VY    = 2;
constexpr int SROWS = VY + 8;         // 10 staged rows
constexpr int SCOLS = 72;             // 64 + 8 halo
constexpr int TPX   = 64 * VY;        // 128 px per block
constexpr int CBLK  = BHWn / TPX;     // 1152 blocks
constexpr int TPI   = HWn / TPX;      // 288 tiles per image
constexpr int GSS   = 800;            // gsum floats per step

typedef __attribute__((ext_vector_type(8))) short short8;
typedef __attribute__((ext_vector_type(4))) float f32x4;

static __device__ __forceinline__ unsigned f2bfu(float f) {
    union { float f; unsigned u; } v; v.f = f;
    return (v.u + 0x7FFFu + ((v.u >> 16) & 1u)) >> 16;   // RNE
}
static __device__ __forceinline__ short f2bf(float f) { return (short)f2bfu(f); }
static __device__ __forceinline__ unsigned pk2(float a, float b) {
    return f2bfu(a) | (f2bfu(b) << 16);
}
static __device__ __forceinline__ float asf(unsigned u) {
    union { unsigned u; float f; } v; v.u = u; return v.f;
}
static __device__ __forceinline__ int refl(int v, int n) {
    v = v < 0 ? -v : v;
    v = v >= n ? 2 * n - 2 - v : v;
    return v;
}

// ---------------------------------------------------------------------------
// One-time prep: wtc[tap][c] = w_p0[c][tap]; w1f fc1 B-frags (round-5
// verified layout); zero the per-step moment accumulators.
// ---------------------------------------------------------------------------
__global__ void k_prep(const float* __restrict__ wp,    // [16][81]
                       const float* __restrict__ wfc1,  // [16][128]
                       float* __restrict__ wtc,         // [81][16]
                       short* __restrict__ w1f,         // [4][64][8]
                       float* __restrict__ gsum)        // [10][800]
{
    int tid = threadIdx.x;
    for (int i = tid; i < KSn * KSn * Cn; i += 256) {
        int t = i / Cn, c = i - t * Cn;
        wtc[i] = wp[c * (KSn * KSn) + t];
    }
    for (int i = tid; i < 4 * 64 * 8; i += 256) {
        int ks = i >> 9;
        int rem = i & 511;
        int l = rem >> 3, j = rem & 7;
        w1f[i] = f2bf(wfc1[(l & 15) * HIDn + ks * 32 + (l >> 4) * 8 + j]);
    }
    for (int i = tid; i < STEPSn * GSS; i += 256) gsum[i] = 0.f;
}

// ---------------------------------------------------------------------------
// k_conv: bf16-staged depthwise 9x9 reflect conv (round-5 verified) ->
// dx bf16 [BHW][32] coalesced store + dx moments (M2 quadrants + means)
// via MFMA with atomicAdd into gs[800].
// gs layout: [0..255] M2(c<16,c'<16), [256..511] M2(c<16,c'>=16),
//            [512..767] M2(c>=16,c'>=16), [768..799] sum(dx[c]).
// ---------------------------------------------------------------------------
__global__ __launch_bounds__(256) void k_conv(
    const float* __restrict__ xin,    // [BHW][16] fp32
    const float* __restrict__ wtc,    // [81][16]
    const float* __restrict__ bp,     // [16]
    unsigned* __restrict__ dxgu,      // [BHW][16 u32] (32 bf16/px)
    float* __restrict__ gs)           // [800] this step's moments
{
    __shared__ __align__(16) char smraw[4 * SROWS * SCOLS * 8];  // 23040 B
    uint2* stg = (uint2*)smraw;                        // [4][10][72] bf16x4
    unsigned* sdx = (unsigned*)smraw;                  // [128][20] u32 (aliases)

    int tid  = threadIdx.x;
    int lane = tid & 63;
    int w    = __builtin_amdgcn_readfirstlane(tid >> 6);
    int l15  = lane & 15;
    int kg   = lane >> 4;

    int blk = blockIdx.x;
    int b   = blk / TPI;
    int t   = blk - b * TPI;
    int ty  = t / 3;
    int tx  = t - ty * 3;
    int y0  = ty * VY;
    int x0  = tx * 64;

    // ---- stage x tile as bf16 (own quad region) ----
    const float4* xb4 = (const float4*)(xin + (size_t)b * HWn * Cn);
    int rrow[SROWS];
#pragma unroll
    for (int ri = 0; ri < SROWS; ++ri)
        rrow[ri] = refl(y0 + ri - PADn, Hn) * (Wn * 4);

    uint2* stw = stg + w * (SROWS * SCOLS);
#pragma unroll
    for (int it = 0; it < 12; ++it) {
        int e = it * 64 + lane;
        if (e < SROWS * SCOLS) {
            int ri  = e / SCOLS;
            int col = e - ri * SCOLS;
            int gc  = refl(x0 + col - PADn, Wn);
            float4 v = xb4[rrow[ri] + gc * 4 + w];
            stw[e] = make_uint2(pk2(v.x, v.y), pk2(v.z, v.w));
        }
    }

    // ---- conv: 2 output rows, quad w; batched taps (round-5 exact) ----
    const float4* wt4 = (const float4*)wtc;
    float4 bq = ((const float4*)bp)[w];
    float4 a0 = bq, a1 = bq;
    uint2 cen0, cen1;
#pragma unroll
    for (int ri = 0; ri < SROWS; ++ri) {
        uint2 tv[KSn];
#pragma unroll
        for (int dx = 0; dx < KSn; ++dx) tv[dx] = stw[ri * SCOLS + lane + dx];
        if (ri == 4) cen0 = tv[4];
        if (ri == 5) cen1 = tv[4];
#pragma unroll
        for (int dx = 0; dx < KSn; ++dx) {
            float c0 = asf(tv[dx].x << 16), c1 = asf(tv[dx].x & 0xffff0000u);
            float c2 = asf(tv[dx].y << 16), c3 = asf(tv[dx].y & 0xffff0000u);
            if (ri <= 8) {
                float4 q = wt4[(ri * KSn + dx) * 4 + w];          // s_load
                a0.x = fmaf(q.x, c0, a0.x); a0.y = fmaf(q.y, c1, a0.y);
                a0.z = fmaf(q.z, c2, a0.z); a0.w = fmaf(q.w, c3, a0.w);
            }
            if (ri >= 1) {
                float4 q = wt4[((ri - 1) * KSn + dx) * 4 + w];    // s_load
                a1.x = fmaf(q.x, c0, a1.x); a1.y = fmaf(q.y, c1, a1.y);
                a1.z = fmaf(q.z, c2, a1.z); a1.w = fmaf(q.w, c3, a1.w);
            }
        }
    }
    __syncthreads();   // all stg reads done before sdx overwrite

    // ---- dxv -> sdx [128 px][20 u32] (u16 idx c = ch 0..31) ----
#pragma unroll
    for (int r = 0; r < VY; ++r) {
        int px = r * 64 + lane;
        uint2 cv  = r ? cen1 : cen0;
        float4 av = r ? a1 : a0;
        unsigned* row = sdx + px * 20;
        *(uint2*)(row + 2 * w)     = cv;
        *(uint2*)(row + 8 + 2 * w) = make_uint2(pk2(av.x, av.y), pk2(av.z, av.w));
    }
    __syncthreads();

    // ---- dx global store, coalesced: 4 threads per px, uint4 each ----
#pragma unroll
    for (int it = 0; it < 2; ++it) {
        int slot = it * 256 + tid;          // 0..511
        int px   = slot >> 2;
        int q    = slot & 3;
        uint4 v  = *(const uint4*)(sdx + px * 20 + q * 4);
        int gp   = b * HWn + (y0 + (px >> 6)) * Wn + x0 + (px & 63);
        *(uint4*)(dxgu + (size_t)gp * 16 + q * 4) = v;
    }

    // ---- moments via MFMA: wave roles ----
    const unsigned short* sdu = (const unsigned short*)smraw;
    if (w == 3) {
        // means: two m-tiles (ch 0-15, 16-31) x ones
        short8 ones;
#pragma unroll
        for (int j = 0; j < 8; ++j) ones[j] = (short)0x3F80;
        f32x4 m0 = {0.f, 0.f, 0.f, 0.f}, m1 = {0.f, 0.f, 0.f, 0.f};
#pragma unroll
        for (int tt = 0; tt < 4; ++tt) {
            short8 fL, fH;
#pragma unroll
            for (int j = 0; j < 8; ++j) {
                int pk = tt * 32 + kg * 8 + j;
                fL[j] = (short)sdu[pk * 40 + l15];
                fH[j] = (short)sdu[pk * 40 + 16 + l15];
            }
            m0 = __builtin_amdgcn_mfma_f32_16x16x32_bf16(fL, ones, m0, 0, 0, 0);
            m1 = __builtin_amdgcn_mfma_f32_16x16x32_bf16(fH, ones, m1, 0, 0, 0);
        }
        if (l15 == 0) {
#pragma unroll
            for (int r = 0; r < 4; ++r) {
                atomicAdd(gs + 768 + 4 * kg + r, m0[r]);
                atomicAdd(gs + 768 + 16 + 4 * kg + r, m1[r]);
            }
        }
    } else {
        // quadrants: w0 (0,0), w1 (0,1), w2 (1,1)
        int mt = (w == 2) ? 1 : 0;
        int nt = (w == 0) ? 0 : 1;
        f32x4 acc = {0.f, 0.f, 0.f, 0.f};
#pragma unroll
        for (int tt = 0; tt < 4; ++tt) {
            short8 fA, fB;
#pragma unroll
            for (int j = 0; j < 8; ++j) {
                int pk = tt * 32 + kg * 8 + j;
                fA[j] = (short)sdu[pk * 40 + mt * 16 + l15];
                fB[j] = (mt == nt) ? fA[j] : (short)sdu[pk * 40 + nt * 16 + l15];
            }
            acc = __builtin_amdgcn_mfma_f32_16x16x32_bf16(fA, fB, acc, 0, 0, 0);
        }
#pragma unroll
        for (int r = 0; r < 4; ++r)
            atomicAdd(gs + w * 256 + (4 * kg + r) * 16 + l15, acc[r]);
    }
}

// ---------------------------------------------------------------------------
// k_stats2 (1 block): moments -> mean/var per hidden channel -> fold BN into
// fc0: bfragp = bf16(gamma*rstd*W0) in MFMA B-frag layout; biasp = folded bias.
// ---------------------------------------------------------------------------
__global__ __launch_bounds__(256) void k_stats2(
    const float* __restrict__ gs,     // [800]
    const float* __restrict__ wfc0,   // [128][32]
    const float* __restrict__ bfc0,   // [128]
    const float* __restrict__ gamma,
    const float* __restrict__ beta,
    short* __restrict__ bfragp,       // [8][64][8]
    float* __restrict__ biasp)        // [128]
{
    __shared__ float M2s[32][32];
    __shared__ float ms[32];
    int tid = threadIdx.x;
    const float inv = 1.0f / BHWn;

    for (int i = tid; i < 1024; i += 256) {
        int c = i >> 5, cp = i & 31;
        float v;
        if (c < 16 && cp < 16)       v = gs[c * 16 + cp];
        else if (c < 16)             v = gs[256 + c * 16 + (cp - 16)];
        else if (cp >= 16)           v = gs[512 + (c - 16) * 16 + (cp - 16)];
        else                         v = gs[256 + cp * 16 + (c - 16)];  // symmetry
        M2s[c][cp] = v * inv;
    }
    if (tid < 32) ms[tid] = gs[768 + tid] * inv;
    __syncthreads();

    if (tid < HIDn) {
        int o = tid;
        float wv[32];
#pragma unroll
        for (int c = 0; c < 32; ++c) wv[c] = wfc0[o * 32 + c];
        float wm = 0.f;
#pragma unroll
        for (int c = 0; c < 32; ++c) wm += wv[c] * ms[c];
        float quad = 0.f;
#pragma unroll 4
        for (int c = 0; c < 32; ++c) {
            float ra = 0.f;
#pragma unroll
            for (int cp = 0; cp < 32; ++cp) ra += wv[cp] * M2s[c][cp];
            quad += wv[c] * ra;
        }
        float b0   = bfc0[o];
        float mu   = wm + b0;
        float Eh2  = quad + 2.f * b0 * wm + b0 * b0;
        float var  = Eh2 - mu * mu;
        float gr   = gamma[o] * rsqrtf(var + EPSf);
        biasp[o]   = beta[o] + gr * (b0 - mu);
        int ntile = o >> 4, l = o & 15;
#pragma unroll
        for (int kg = 0; kg < 4; ++kg)
#pragma unroll
            for (int j = 0; j < 8; ++j)
                bfragp[ntile * 512 + (l + 16 * kg) * 8 + j] = f2bf(gr * wv[kg * 8 + j]);
    }
}

// ---------------------------------------------------------------------------
// k_fc: fc0' MFMA (folded BN) + ReLU + per-wave LDS transpose + fc1 MFMA +
// masked x update (round-5 verified writeout). 64 px/block, 16 px/wave.
// ---------------------------------------------------------------------------
__global__ __launch_bounds__(256) void k_fc(
    const float* __restrict__ xin,    // [BHW][16]
    const unsigned* __restrict__ dxgu,// [BHW][16 u32]
    const short* __restrict__ bfragp, // [8][64][8]
    const float* __restrict__ biasp,  // [128]
    const short* __restrict__ w1f,    // [4][64][8]
    const float* __restrict__ uS,     // [BHW]
    float* __restrict__ xout)         // [BHW][16]
{
    __shared__ unsigned short hls[4][16][136];   // 272B rows (16B aligned)

    int tid  = threadIdx.x;
    int lane = tid & 63;
    int w    = __builtin_amdgcn_readfirstlane(tid >> 6);
    int l15  = lane & 15;
    int kg   = lane >> 4;

    int gp0 = blockIdx.x * 64 + w * 16;

    // fc0': A = dx (M=px, K=32ch) -- one uint4 load IS the frag
    union { uint4 u4; short8 s8; } A;
    A.u4 = *(const uint4*)(dxgu + (size_t)(gp0 + l15) * 16 + kg * 4);

    const short8* bgp = (const short8*)bfragp;
#pragma unroll
    for (int nt = 0; nt < 8; ++nt) {
        float bb = biasp[nt * 16 + l15];
        f32x4 c = {bb, bb, bb, bb};
        c = __builtin_amdgcn_mfma_f32_16x16x32_bf16(A.s8, bgp[nt * 64 + lane], c, 0, 0, 0);
#pragma unroll
        for (int r = 0; r < 4; ++r) {
            float hv = fmaxf(c[r], 0.f);
            hls[w][4 * kg + r][nt * 16 + l15] = (unsigned short)f2bfu(hv);
        }
    }
    __syncthreads();

    // fc1: A = hn (M=px, K=128) from LDS rows; B = w1f (verified layout)
    const short8* wfp = (const short8*)w1f;
    f32x4 d = {0.f, 0.f, 0.f, 0.f};
#pragma unroll
    for (int ks = 0; ks < 4; ++ks) {
        short8 af = *(const short8*)&hls[w][l15][ks * 32 + kg * 8];
        d = __builtin_amdgcn_mfma_f32_16x16x32_bf16(af, wfp[ks * 64 + lane], d, 0, 0, 0);
    }

    // masked update: lane holds d[px = gp0+4kg+r][ch = l15]; ch 0 frozen
#pragma unroll
    for (int r = 0; r < 4; ++r) {
        int gp = gp0 + 4 * kg + r;
        float uu   = uS[gp];
        float xold = xin[(size_t)gp * Cn + l15];
        float add  = (uu > FIREf && l15 != 0) ? d[r] : 0.f;
        xout[(size_t)gp * Cn + l15] = xold + add;
    }
}

// ---------------------------------------------------------------------------
extern "C" void kernel_launch(void* const* d_in, const int* in_sizes, int n_in,
                              void* d_out, int out_size, void* d_ws, size_t ws_size,
                              hipStream_t stream) {
    const float* x0   = (const float*)d_in[0];
    const float* ru   = (const float*)d_in[1];
    const float* wp   = (const float*)d_in[2];
    const float* bp   = (const float*)d_in[3];
    const float* wfc0 = (const float*)d_in[4];
    const float* bfc0 = (const float*)d_in[5];
    const float* wfc1 = (const float*)d_in[6];
    const float* gm   = (const float*)d_in[7];
    const float* bt   = (const float*)d_in[8];
    float*       out  = (float*)d_out;

    float* ws     = (float*)d_ws;
    float* bufA   = ws;                                  // 2,359,296 f
    float* bufB   = bufA + (size_t)BHWn * Cn;            // 2,359,296 f
    float* wtc    = bufB + (size_t)BHWn * Cn;            // 1312 f
    short* w1f    = (short*)(wtc + 1312);                // 2048 s = 1024 f
    short* bfragp = w1f + 2048;                          // 4096 s = 2048 f
    float* biasp  = (float*)(bfragp + 4096);             // 128 f
    float* gsum   = biasp + 128;                         // 8000 f
    unsigned* dxg = (unsigned*)(gsum + 8000);            // 2,359,296 u32

    k_prep<<<1, 256, 0, stream>>>(wp, wfc1, wtc, w1f, gsum);

    const float* xcur = x0;
    for (int s = 0; s < STEPSn; ++s) {
        float* gs = gsum + s * GSS;
        float* xo = (s == STEPSn - 1) ? out : ((s & 1) ? bufB : bufA);
        k_conv<<<CBLK, 256, 0, stream>>>(xcur, wtc, bp, dxg, gs);
        k_stats2<<<1, 256, 0, stream>>>(gs, wfc0, bfc0, gm, bt, bfragp, biasp);
        k_fc<<<BHWn / 64, 256, 0, stream>>>(xcur, dxg, bfragp, biasp, w1f,
                                            ru + (size_t)s * BHWn, xo);
        xcur = xo;
    }
}

// Round 9
// 585.914 us; speedup vs baseline: 1.7152x; 1.7152x over previous
//
#include <hip/hip_runtime.h>

// Problem constants
constexpr int Bn    = 4;
constexpr int Hn    = 192;
constexpr int Wn    = 192;
constexpr int Cn    = 16;
constexpr int HIDn  = 128;
constexpr int HWn   = Hn * Wn;        // 36864
constexpr int BHWn  = Bn * HWn;       // 147456
constexpr int STEPSn = 10;
constexpr int PADn  = 4;
constexpr int KSn   = 9;
constexpr float EPSf  = 1e-5f;
constexpr float FIREf = 0.5f;

// conv kernel geometry: 64 cols x 2 rows per block, 4 waves (channel quads)
constexpr int VY    = 2;
constexpr int SCOLS = 72;             // 64 + 8 halo
constexpr int TPX   = 64 * VY;        // 128 px per block
constexpr int CBLK  = BHWn / TPX;     // 1152 blocks
constexpr int TPI   = HWn / TPX;      // 288 tiles per image
constexpr int GSS   = 800;            // moment floats per copy
constexpr int NCOP  = 32;             // partial copies (contention spread)

typedef __attribute__((ext_vector_type(8))) short short8;
typedef __attribute__((ext_vector_type(4))) float f32x4;

static __device__ __forceinline__ unsigned f2bfu(float f) {
    union { float f; unsigned u; } v; v.f = f;
    return (v.u + 0x7FFFu + ((v.u >> 16) & 1u)) >> 16;   // RNE
}
static __device__ __forceinline__ short f2bf(float f) { return (short)f2bfu(f); }
static __device__ __forceinline__ unsigned pk2(float a, float b) {
    return f2bfu(a) | (f2bfu(b) << 16);
}
static __device__ __forceinline__ float asf(unsigned u) {
    union { unsigned u; float f; } v; v.u = u; return v.f;
}
static __device__ __forceinline__ int refl(int v, int n) {
    v = v < 0 ? -v : v;
    v = v >= n ? 2 * n - 2 - v : v;
    return v;
}

// ---------------------------------------------------------------------------
// Prep (grid-strided, 64 blocks): zero moment partials; block 0 also builds
// wtc[tap][c] and fc1 B-frags (round-5 verified layout).
// ---------------------------------------------------------------------------
__global__ void k_prep(const float* __restrict__ wp,    // [16][81]
                       const float* __restrict__ wfc1,  // [16][128]
                       float* __restrict__ wtc,         // [81][16]
                       short* __restrict__ w1f,         // [4][64][8]
                       float* __restrict__ gsum)        // [10][NCOP][800]
{
    int gid = blockIdx.x * 256 + threadIdx.x;
    for (int i = gid; i < STEPSn * NCOP * GSS; i += gridDim.x * 256) gsum[i] = 0.f;
    if (blockIdx.x == 0) {
        int tid = threadIdx.x;
        for (int i = tid; i < KSn * KSn * Cn; i += 256) {
            int t = i / Cn, c = i - t * Cn;
            wtc[i] = wp[c * (KSn * KSn) + t];
        }
        for (int i = tid; i < 4 * 64 * 8; i += 256) {
            int ks = i >> 9;
            int rem = i & 511;
            int l = rem >> 3, j = rem & 7;
            w1f[i] = f2bf(wfc1[(l & 15) * HIDn + ks * 32 + (l >> 4) * 8 + j]);
        }
    }
}

// ---------------------------------------------------------------------------
// k_conv: two-phase bf16 LDS staging + depthwise 9x9 reflect conv ->
// dx bf16 [BHW][32] store + dx moments via MFMA, atomicAdd into copy blk&31.
// LDS = 13824 B -> ~4 blocks/CU.
// gs copy layout: [0..255] M2(LL), [256..511] M2(LH), [512..767] M2(HH),
//                 [768..799] mean sums.
// ---------------------------------------------------------------------------
__global__ __launch_bounds__(256) void k_conv(
    const float* __restrict__ xin,    // [BHW][16] fp32
    const float* __restrict__ wtc,    // [81][16]
    const float* __restrict__ bp,     // [16]
    unsigned* __restrict__ dxgu,      // [BHW][16 u32] (32 bf16/px)
    float* __restrict__ gsb)          // [NCOP][800] this step
{
    __shared__ __align__(16) char smraw[4 * 6 * SCOLS * 8];  // 13824 B
    uint2* stg = (uint2*)smraw;                        // [4][6][72] bf16x4
    unsigned* sdx = (unsigned*)smraw;                  // [128][20] u32 (alias)

    int tid  = threadIdx.x;
    int lane = tid & 63;
    int w    = __builtin_amdgcn_readfirstlane(tid >> 6);
    int l15  = lane & 15;
    int kg   = lane >> 4;

    int blk = blockIdx.x;
    int b   = blk / TPI;
    int t   = blk - b * TPI;
    int ty  = t / 3;
    int tx  = t - ty * 3;
    int y0  = ty * VY;
    int x0  = tx * 64;

    const float4* xb4 = (const float4*)(xin + (size_t)b * HWn * Cn);
    int rrow[10];
#pragma unroll
    for (int ri = 0; ri < 10; ++ri)
        rrow[ri] = refl(y0 + ri - PADn, Hn) * (Wn * 4);

    const float4* wt4 = (const float4*)wtc;
    float4 bq = ((const float4*)bp)[w];
    float4 a0 = bq, a1 = bq;
    uint2 cen0, cen1;
    uint2* stw = stg + w * (6 * SCOLS);

    // ---- phase A: stage rows 0..5 (own quad; wave-local, no barrier) ----
#pragma unroll
    for (int it = 0; it < 7; ++it) {
        int e = it * 64 + lane;
        if (e < 6 * SCOLS) {
            int ri  = e / SCOLS;
            int col = e - ri * SCOLS;
            int gc  = refl(x0 + col - PADn, Wn);
            float4 v = xb4[rrow[ri] + gc * 4 + w];
            stw[e] = make_uint2(pk2(v.x, v.y), pk2(v.z, v.w));
        }
    }
#pragma unroll
    for (int ri = 0; ri < 6; ++ri) {
        uint2 tv[KSn];
#pragma unroll
        for (int dx = 0; dx < KSn; ++dx) tv[dx] = stw[ri * SCOLS + lane + dx];
        if (ri == 4) cen0 = tv[4];
        if (ri == 5) cen1 = tv[4];
#pragma unroll
        for (int dx = 0; dx < KSn; ++dx) {
            float c0 = asf(tv[dx].x << 16), c1 = asf(tv[dx].x & 0xffff0000u);
            float c2 = asf(tv[dx].y << 16), c3 = asf(tv[dx].y & 0xffff0000u);
            {
                float4 q = wt4[(ri * KSn + dx) * 4 + w];          // s_load
                a0.x = fmaf(q.x, c0, a0.x); a0.y = fmaf(q.y, c1, a0.y);
                a0.z = fmaf(q.z, c2, a0.z); a0.w = fmaf(q.w, c3, a0.w);
            }
            if (ri >= 1) {
                float4 q = wt4[((ri - 1) * KSn + dx) * 4 + w];    // s_load
                a1.x = fmaf(q.x, c0, a1.x); a1.y = fmaf(q.y, c1, a1.y);
                a1.z = fmaf(q.z, c2, a1.z); a1.w = fmaf(q.w, c3, a1.w);
            }
        }
    }

    // ---- phase B: stage rows 6..9 into slots 0..3 (wave-local) ----
#pragma unroll
    for (int it = 0; it < 5; ++it) {
        int e = it * 64 + lane;
        if (e < 4 * SCOLS) {
            int ri  = e / SCOLS;               // +6 global
            int col = e - ri * SCOLS;
            int gc  = refl(x0 + col - PADn, Wn);
            float4 v = xb4[rrow[ri + 6] + gc * 4 + w];
            stw[e] = make_uint2(pk2(v.x, v.y), pk2(v.z, v.w));
        }
    }
#pragma unroll
    for (int rr = 0; rr < 4; ++rr) {           // global ri = rr + 6
        uint2 tv[KSn];
#pragma unroll
        for (int dx = 0; dx < KSn; ++dx) tv[dx] = stw[rr * SCOLS + lane + dx];
#pragma unroll
        for (int dx = 0; dx < KSn; ++dx) {
            float c0 = asf(tv[dx].x << 16), c1 = asf(tv[dx].x & 0xffff0000u);
            float c2 = asf(tv[dx].y << 16), c3 = asf(tv[dx].y & 0xffff0000u);
            if (rr <= 2) {
                float4 q = wt4[((rr + 6) * KSn + dx) * 4 + w];
                a0.x = fmaf(q.x, c0, a0.x); a0.y = fmaf(q.y, c1, a0.y);
                a0.z = fmaf(q.z, c2, a0.z); a0.w = fmaf(q.w, c3, a0.w);
            }
            {
                float4 q = wt4[((rr + 5) * KSn + dx) * 4 + w];
                a1.x = fmaf(q.x, c0, a1.x); a1.y = fmaf(q.y, c1, a1.y);
                a1.z = fmaf(q.z, c2, a1.z); a1.w = fmaf(q.w, c3, a1.w);
            }
        }
    }
    __syncthreads();   // ALL waves' staging reads done before sdx overwrite

    // ---- dxv -> sdx [128 px][20 u32] ----
#pragma unroll
    for (int r = 0; r < VY; ++r) {
        int px = r * 64 + lane;
        uint2 cv  = r ? cen1 : cen0;
        float4 av = r ? a1 : a0;
        unsigned* row = sdx + px * 20;
        *(uint2*)(row + 2 * w)     = cv;
        *(uint2*)(row + 8 + 2 * w) = make_uint2(pk2(av.x, av.y), pk2(av.z, av.w));
    }
    __syncthreads();

    // ---- dx global store, coalesced: 4 threads per px, uint4 each ----
#pragma unroll
    for (int it = 0; it < 2; ++it) {
        int slot = it * 256 + tid;          // 0..511
        int px   = slot >> 2;
        int q    = slot & 3;
        uint4 v  = *(const uint4*)(sdx + px * 20 + q * 4);
        int gp   = b * HWn + (y0 + (px >> 6)) * Wn + x0 + (px & 63);
        *(uint4*)(dxgu + (size_t)gp * 16 + q * 4) = v;
    }

    // ---- moments via MFMA (round-8 verified mappings) ----
    float* gs = gsb + (size_t)(blk & (NCOP - 1)) * GSS;
    const unsigned short* sdu = (const unsigned short*)smraw;
    if (w == 3) {
        short8 ones;
#pragma unroll
        for (int j = 0; j < 8; ++j) ones[j] = (short)0x3F80;
        f32x4 m0 = {0.f, 0.f, 0.f, 0.f}, m1 = {0.f, 0.f, 0.f, 0.f};
#pragma unroll
        for (int tt = 0; tt < 4; ++tt) {
            short8 fL, fH;
#pragma unroll
            for (int j = 0; j < 8; ++j) {
                int pk = tt * 32 + kg * 8 + j;
                fL[j] = (short)sdu[pk * 40 + l15];
                fH[j] = (short)sdu[pk * 40 + 16 + l15];
            }
            m0 = __builtin_amdgcn_mfma_f32_16x16x32_bf16(fL, ones, m0, 0, 0, 0);
            m1 = __builtin_amdgcn_mfma_f32_16x16x32_bf16(fH, ones, m1, 0, 0, 0);
        }
        if (l15 == 0) {
#pragma unroll
            for (int r = 0; r < 4; ++r) {
                atomicAdd(gs + 768 + 4 * kg + r, m0[r]);
                atomicAdd(gs + 768 + 16 + 4 * kg + r, m1[r]);
            }
        }
    } else {
        int mt = (w == 2) ? 1 : 0;
        int nt = (w == 0) ? 0 : 1;
        f32x4 acc = {0.f, 0.f, 0.f, 0.f};
#pragma unroll
        for (int tt = 0; tt < 4; ++tt) {
            short8 fA, fB;
#pragma unroll
            for (int j = 0; j < 8; ++j) {
                int pk = tt * 32 + kg * 8 + j;
                fA[j] = (short)sdu[pk * 40 + mt * 16 + l15];
                fB[j] = (mt == nt) ? fA[j] : (short)sdu[pk * 40 + nt * 16 + l15];
            }
            acc = __builtin_amdgcn_mfma_f32_16x16x32_bf16(fA, fB, acc, 0, 0, 0);
        }
#pragma unroll
        for (int r = 0; r < 4; ++r)
            atomicAdd(gs + w * 256 + (4 * kg + r) * 16 + l15, acc[r]);
    }
}

// ---------------------------------------------------------------------------
// k_stats2 (1 block): reduce NCOP copies -> moments -> fold BN into fc0
// (round-8 verified math): bfragp = bf16(gr*W0) B-frags, biasp folded.
// ---------------------------------------------------------------------------
__global__ __launch_bounds__(256) void k_stats2(
    const float* __restrict__ gsb,    // [NCOP][800]
    const float* __restrict__ wfc0,   // [128][32]
    const float* __restrict__ bfc0,   // [128]
    const float* __restrict__ gamma,
    const float* __restrict__ beta,
    short* __restrict__ bfragp,       // [8][64][8]
    float* __restrict__ biasp)        // [128]
{
    __shared__ float gsr[GSS];
    __shared__ float M2s[32][32];
    __shared__ float ms[32];
    int tid = threadIdx.x;
    const float inv = 1.0f / BHWn;

    for (int e = tid; e < GSS; e += 256) {
        float acc = 0.f;
#pragma unroll 8
        for (int c2 = 0; c2 < NCOP; ++c2) acc += gsb[c2 * GSS + e];
        gsr[e] = acc;
    }
    __syncthreads();

    for (int i = tid; i < 1024; i += 256) {
        int c = i >> 5, cp = i & 31;
        float v;
        if (c < 16 && cp < 16)       v = gsr[c * 16 + cp];
        else if (c < 16)             v = gsr[256 + c * 16 + (cp - 16)];
        else if (cp >= 16)           v = gsr[512 + (c - 16) * 16 + (cp - 16)];
        else                         v = gsr[256 + cp * 16 + (c - 16)];  // symmetry
        M2s[c][cp] = v * inv;
    }
    if (tid < 32) ms[tid] = gsr[768 + tid] * inv;
    __syncthreads();

    if (tid < HIDn) {
        int o = tid;
        float wv[32];
#pragma unroll
        for (int c = 0; c < 32; ++c) wv[c] = wfc0[o * 32 + c];
        float wm = 0.f;
#pragma unroll
        for (int c = 0; c < 32; ++c) wm += wv[c] * ms[c];
        float quad = 0.f;
#pragma unroll 4
        for (int c = 0; c < 32; ++c) {
            float ra = 0.f;
#pragma unroll
            for (int cp = 0; cp < 32; ++cp) ra += wv[cp] * M2s[c][cp];
            quad += wv[c] * ra;
        }
        float b0   = bfc0[o];
        float mu   = wm + b0;
        float Eh2  = quad + 2.f * b0 * wm + b0 * b0;
        float var  = Eh2 - mu * mu;
        float gr   = gamma[o] * rsqrtf(var + EPSf);
        biasp[o]   = beta[o] + gr * (b0 - mu);
        int ntile = o >> 4, l = o & 15;
#pragma unroll
        for (int kg = 0; kg < 4; ++kg)
#pragma unroll
            for (int j = 0; j < 8; ++j)
                bfragp[ntile * 512 + (l + 16 * kg) * 8 + j] = f2bf(gr * wv[kg * 8 + j]);
    }
}

// ---------------------------------------------------------------------------
// k_fc: fc0' MFMA (folded BN) + ReLU + per-wave LDS transpose + fc1 MFMA +
// masked x update (round-8 verified). 64 px/block, 16 px/wave.
// ---------------------------------------------------------------------------
__global__ __launch_bounds__(256) void k_fc(
    const float* __restrict__ xin,    // [BHW][16]
    const unsigned* __restrict__ dxgu,// [BHW][16 u32]
    const short* __restrict__ bfragp, // [8][64][8]
    const float* __restrict__ biasp,  // [128]
    const short* __restrict__ w1f,    // [4][64][8]
    const float* __restrict__ uS,     // [BHW]
    float* __restrict__ xout)         // [BHW][16]
{
    __shared__ unsigned short hls[4][16][136];

    int tid  = threadIdx.x;
    int lane = tid & 63;
    int w    = __builtin_amdgcn_readfirstlane(tid >> 6);
    int l15  = lane & 15;
    int kg   = lane >> 4;

    int gp0 = blockIdx.x * 64 + w * 16;

    union { uint4 u4; short8 s8; } A;
    A.u4 = *(const uint4*)(dxgu + (size_t)(gp0 + l15) * 16 + kg * 4);

    const short8* bgp = (const short8*)bfragp;
#pragma unroll
    for (int nt = 0; nt < 8; ++nt) {
        float bb = biasp[nt * 16 + l15];
        f32x4 c = {bb, bb, bb, bb};
        c = __builtin_amdgcn_mfma_f32_16x16x32_bf16(A.s8, bgp[nt * 64 + lane], c, 0, 0, 0);
#pragma unroll
        for (int r = 0; r < 4; ++r) {
            float hv = fmaxf(c[r], 0.f);
            hls[w][4 * kg + r][nt * 16 + l15] = (unsigned short)f2bfu(hv);
        }
    }
    __syncthreads();

    const short8* wfp = (const short8*)w1f;
    f32x4 d = {0.f, 0.f, 0.f, 0.f};
#pragma unroll
    for (int ks = 0; ks < 4; ++ks) {
        short8 af = *(const short8*)&hls[w][l15][ks * 32 + kg * 8];
        d = __builtin_amdgcn_mfma_f32_16x16x32_bf16(af, wfp[ks * 64 + lane], d, 0, 0, 0);
    }

#pragma unroll
    for (int r = 0; r < 4; ++r) {
        int gp = gp0 + 4 * kg + r;
        float uu   = uS[gp];
        float xold = xin[(size_t)gp * Cn + l15];
        float add  = (uu > FIREf && l15 != 0) ? d[r] : 0.f;
        xout[(size_t)gp * Cn + l15] = xold + add;
    }
}

// ---------------------------------------------------------------------------
extern "C" void kernel_launch(void* const* d_in, const int* in_sizes, int n_in,
                              void* d_out, int out_size, void* d_ws, size_t ws_size,
                              hipStream_t stream) {
    const float* x0   = (const float*)d_in[0];
    const float* ru   = (const float*)d_in[1];
    const float* wp   = (const float*)d_in[2];
    const float* bp   = (const float*)d_in[3];
    const float* wfc0 = (const float*)d_in[4];
    const float* bfc0 = (const float*)d_in[5];
    const float* wfc1 = (const float*)d_in[6];
    const float* gm   = (const float*)d_in[7];
    const float* bt   = (const float*)d_in[8];
    float*       out  = (float*)d_out;

    float* ws     = (float*)d_ws;
    float* bufA   = ws;                                  // 2,359,296 f
    float* bufB   = bufA + (size_t)BHWn * Cn;            // 2,359,296 f
    float* wtc    = bufB + (size_t)BHWn * Cn;            // 1312 f
    short* w1f    = (short*)(wtc + 1312);                // 2048 s
    short* bfragp = w1f + 2048;                          // 4096 s
    float* biasp  = (float*)(bfragp + 4096);             // 128 f
    float* gsum   = biasp + 128;                         // 10*NCOP*800 f
    unsigned* dxg = (unsigned*)(gsum + STEPSn * NCOP * GSS);  // 2,359,296 u32

    k_prep<<<64, 256, 0, stream>>>(wp, wfc1, wtc, w1f, gsum);

    const float* xcur = x0;
    for (int s = 0; s < STEPSn; ++s) {
        float* gsb = gsum + (size_t)s * NCOP * GSS;
        float* xo = (s == STEPSn - 1) ? out : ((s & 1) ? bufB : bufA);
        k_conv<<<CBLK, 256, 0, stream>>>(xcur, wtc, bp, dxg, gsb);
        k_stats2<<<1, 256, 0, stream>>>(gsb, wfc0, bfc0, gm, bt, bfragp, biasp);
        k_fc<<<BHWn / 64, 256, 0, stream>>>(xcur, dxg, bfragp, biasp, w1f,
                                            ru + (size_t)s * BHWn, xo);
        xcur = xo;
    }
}

// Round 10
// 566.267 us; speedup vs baseline: 1.7747x; 1.0347x over previous
//
#include <hip/hip_runtime.h>

// Problem constants
constexpr int Bn    = 4;
constexpr int Hn    = 192;
constexpr int Wn    = 192;
constexpr int Cn    = 16;
constexpr int HIDn  = 128;
constexpr int HWn   = Hn * Wn;        // 36864
constexpr int BHWn  = Bn * HWn;       // 147456
constexpr int STEPSn = 10;
constexpr int PADn  = 4;
constexpr int KSn   = 9;
constexpr float EPSf  = 1e-5f;
constexpr float FIREf = 0.5f;

// conv kernel geometry: 64 cols x 1 row per block, 4 waves (channel quads)
constexpr int SCOLS = 72;             // 64 + 8 halo
constexpr int TPX   = 64;             // 64 px per block
constexpr int CBLK  = BHWn / TPX;     // 2304 blocks
constexpr int TPI   = HWn / TPX;      // 576 tiles per image
constexpr int GSS   = 800;            // moment floats per copy
constexpr int NCOP  = 32;             // partial copies (contention spread)

typedef __attribute__((ext_vector_type(8))) short short8;
typedef __attribute__((ext_vector_type(4))) float f32x4;

static __device__ __forceinline__ unsigned f2bfu(float f) {
    union { float f; unsigned u; } v; v.f = f;
    return (v.u + 0x7FFFu + ((v.u >> 16) & 1u)) >> 16;   // RNE
}
static __device__ __forceinline__ short f2bf(float f) { return (short)f2bfu(f); }
static __device__ __forceinline__ unsigned pk2(float a, float b) {
    return f2bfu(a) | (f2bfu(b) << 16);
}
static __device__ __forceinline__ float asf(unsigned u) {
    union { unsigned u; float f; } v; v.u = u; return v.f;
}
static __device__ __forceinline__ int refl(int v, int n) {
    v = v < 0 ? -v : v;
    v = v >= n ? 2 * n - 2 - v : v;
    return v;
}

// ---------------------------------------------------------------------------
// Prep (grid-strided, 64 blocks): zero moment partials; block 0 also builds
// wtc[tap][c] and fc1 B-frags (round-5 verified layout).
// ---------------------------------------------------------------------------
__global__ void k_prep(const float* __restrict__ wp,    // [16][81]
                       const float* __restrict__ wfc1,  // [16][128]
                       float* __restrict__ wtc,         // [81][16]
                       short* __restrict__ w1f,         // [4][64][8]
                       float* __restrict__ gsum)        // [10][NCOP][800]
{
    int gid = blockIdx.x * 256 + threadIdx.x;
    for (int i = gid; i < STEPSn * NCOP * GSS; i += gridDim.x * 256) gsum[i] = 0.f;
    if (blockIdx.x == 0) {
        int tid = threadIdx.x;
        for (int i = tid; i < KSn * KSn * Cn; i += 256) {
            int t = i / Cn, c = i - t * Cn;
            wtc[i] = wp[c * (KSn * KSn) + t];
        }
        for (int i = tid; i < 4 * 64 * 8; i += 256) {
            int ks = i >> 9;
            int rem = i & 511;
            int l = rem >> 3, j = rem & 7;
            w1f[i] = f2bf(wfc1[(l & 15) * HIDn + ks * 32 + (l >> 4) * 8 + j]);
        }
    }
}

// ---------------------------------------------------------------------------
// k_conv (VY=1): flat-staged bf16 9-row tile -> 81-tap conv (single acc quad,
// no conditionals) -> dx bf16 [BHW][32] store + dx moments via MFMA (K=64),
// atomicAdd into copy blk&31.
// LDS = [4 quads][9 rows][72 cols] uint2 = 20736 B; sdx [64][20] u32 aliases.
// ---------------------------------------------------------------------------
__global__ __launch_bounds__(256) void k_conv(
    const float* __restrict__ xin,    // [BHW][16] fp32
    const float* __restrict__ wtc,    // [81][16]
    const float* __restrict__ bp,     // [16]
    unsigned* __restrict__ dxgu,      // [BHW][16 u32] (32 bf16/px)
    float* __restrict__ gsb)          // [NCOP][800] this step
{
    __shared__ __align__(16) char smraw[4 * KSn * SCOLS * 8];  // 20736 B
    uint2* stg = (uint2*)smraw;                        // [4][9][72] bf16x4
    unsigned* sdx = (unsigned*)smraw;                  // [64][20] u32 (alias)

    int tid  = threadIdx.x;
    int lane = tid & 63;
    int w    = __builtin_amdgcn_readfirstlane(tid >> 6);
    int l15  = lane & 15;
    int kg   = lane >> 4;

    int blk = blockIdx.x;
    int b   = blk / TPI;
    int t   = blk - b * TPI;
    int y0  = t / 3;                   // output row
    int x0  = (t - y0 * 3) * 64;

    const float4* xb4 = (const float4*)(xin + (size_t)b * HWn * Cn);
    int rrow[KSn];
#pragma unroll
    for (int ri = 0; ri < KSn; ++ri)
        rrow[ri] = refl(y0 + ri - PADn, Hn) * (Wn * 4);

    // ---- stage 9 rows x 72 cols (own quad; wave-local, no barrier) ----
    uint2* stw = stg + w * (KSn * SCOLS);
#pragma unroll
    for (int it = 0; it < 11; ++it) {
        int e = it * 64 + lane;
        if (e < KSn * SCOLS) {
            int ri  = e / SCOLS;
            int col = e - ri * SCOLS;
            int gc  = refl(x0 + col - PADn, Wn);
            float4 v = xb4[rrow[ri] + gc * 4 + w];
            stw[e] = make_uint2(pk2(v.x, v.y), pk2(v.z, v.w));
        }
    }

    // ---- conv: 1 output row, quad w; 81 unconditional taps ----
    const float4* wt4 = (const float4*)wtc;
    float4 a0 = ((const float4*)bp)[w];
    uint2 cen;
#pragma unroll
    for (int ri = 0; ri < KSn; ++ri) {
        uint2 tv[KSn];
#pragma unroll
        for (int dx = 0; dx < KSn; ++dx) tv[dx] = stw[ri * SCOLS + lane + dx];
        if (ri == 4) cen = tv[4];
#pragma unroll
        for (int dx = 0; dx < KSn; ++dx) {
            float c0 = asf(tv[dx].x << 16), c1 = asf(tv[dx].x & 0xffff0000u);
            float c2 = asf(tv[dx].y << 16), c3 = asf(tv[dx].y & 0xffff0000u);
            float4 q = wt4[(ri * KSn + dx) * 4 + w];              // s_load
            a0.x = fmaf(q.x, c0, a0.x); a0.y = fmaf(q.y, c1, a0.y);
            a0.z = fmaf(q.z, c2, a0.z); a0.w = fmaf(q.w, c3, a0.w);
        }
    }
    __syncthreads();   // ALL waves' staging reads done before sdx overwrite

    // ---- dxv -> sdx [64 px][20 u32] (u16 idx = ch 0..31) ----
    {
        unsigned* row = sdx + lane * 20;
        *(uint2*)(row + 2 * w)     = cen;
        *(uint2*)(row + 8 + 2 * w) = make_uint2(pk2(a0.x, a0.y), pk2(a0.z, a0.w));
    }
    __syncthreads();

    // ---- dx global store, coalesced: 4 threads per px, 1 uint4 each ----
    {
        int px = tid >> 2;
        int q  = tid & 3;
        uint4 v = *(const uint4*)(sdx + px * 20 + q * 4);
        int gp  = b * HWn + y0 * Wn + x0 + px;
        *(uint4*)(dxgu + (size_t)gp * 16 + q * 4) = v;
    }

    // ---- moments via MFMA (round-8 verified mappings; K=64 -> 2 tt) ----
    float* gs = gsb + (size_t)(blk & (NCOP - 1)) * GSS;
    const unsigned short* sdu = (const unsigned short*)smraw;
    if (w == 3) {
        short8 ones;
#pragma unroll
        for (int j = 0; j < 8; ++j) ones[j] = (short)0x3F80;
        f32x4 m0 = {0.f, 0.f, 0.f, 0.f}, m1 = {0.f, 0.f, 0.f, 0.f};
#pragma unroll
        for (int tt = 0; tt < 2; ++tt) {
            short8 fL, fH;
#pragma unroll
            for (int j = 0; j < 8; ++j) {
                int pk = tt * 32 + kg * 8 + j;
                fL[j] = (short)sdu[pk * 40 + l15];
                fH[j] = (short)sdu[pk * 40 + 16 + l15];
            }
            m0 = __builtin_amdgcn_mfma_f32_16x16x32_bf16(fL, ones, m0, 0, 0, 0);
            m1 = __builtin_amdgcn_mfma_f32_16x16x32_bf16(fH, ones, m1, 0, 0, 0);
        }
        if (l15 == 0) {
#pragma unroll
            for (int r = 0; r < 4; ++r) {
                atomicAdd(gs + 768 + 4 * kg + r, m0[r]);
                atomicAdd(gs + 768 + 16 + 4 * kg + r, m1[r]);
            }
        }
    } else {
        int mt = (w == 2) ? 1 : 0;
        int nt = (w == 0) ? 0 : 1;
        f32x4 acc = {0.f, 0.f, 0.f, 0.f};
#pragma unroll
        for (int tt = 0; tt < 2; ++tt) {
            short8 fA, fB;
#pragma unroll
            for (int j = 0; j < 8; ++j) {
                int pk = tt * 32 + kg * 8 + j;
                fA[j] = (short)sdu[pk * 40 + mt * 16 + l15];
                fB[j] = (mt == nt) ? fA[j] : (short)sdu[pk * 40 + nt * 16 + l15];
            }
            acc = __builtin_amdgcn_mfma_f32_16x16x32_bf16(fA, fB, acc, 0, 0, 0);
        }
#pragma unroll
        for (int r = 0; r < 4; ++r)
            atomicAdd(gs + w * 256 + (4 * kg + r) * 16 + l15, acc[r]);
    }
}

// ---------------------------------------------------------------------------
// k_stats2 (1 block): reduce NCOP copies -> moments -> fold BN into fc0
// (round-8 verified math): bfragp = bf16(gr*W0) B-frags, biasp folded.
// ---------------------------------------------------------------------------
__global__ __launch_bounds__(256) void k_stats2(
    const float* __restrict__ gsb,    // [NCOP][800]
    const float* __restrict__ wfc0,   // [128][32]
    const float* __restrict__ bfc0,   // [128]
    const float* __restrict__ gamma,
    const float* __restrict__ beta,
    short* __restrict__ bfragp,       // [8][64][8]
    float* __restrict__ biasp)        // [128]
{
    __shared__ float gsr[GSS];
    __shared__ float M2s[32][32];
    __shared__ float ms[32];
    int tid = threadIdx.x;
    const float inv = 1.0f / BHWn;

    for (int e = tid; e < GSS; e += 256) {
        float acc = 0.f;
#pragma unroll 8
        for (int c2 = 0; c2 < NCOP; ++c2) acc += gsb[c2 * GSS + e];
        gsr[e] = acc;
    }
    __syncthreads();

    for (int i = tid; i < 1024; i += 256) {
        int c = i >> 5, cp = i & 31;
        float v;
        if (c < 16 && cp < 16)       v = gsr[c * 16 + cp];
        else if (c < 16)             v = gsr[256 + c * 16 + (cp - 16)];
        else if (cp >= 16)           v = gsr[512 + (c - 16) * 16 + (cp - 16)];
        else                         v = gsr[256 + cp * 16 + (c - 16)];  // symmetry
        M2s[c][cp] = v * inv;
    }
    if (tid < 32) ms[tid] = gsr[768 + tid] * inv;
    __syncthreads();

    if (tid < HIDn) {
        int o = tid;
        float wv[32];
#pragma unroll
        for (int c = 0; c < 32; ++c) wv[c] = wfc0[o * 32 + c];
        float wm = 0.f;
#pragma unroll
        for (int c = 0; c < 32; ++c) wm += wv[c] * ms[c];
        float quad = 0.f;
#pragma unroll 4
        for (int c = 0; c < 32; ++c) {
            float ra = 0.f;
#pragma unroll
            for (int cp = 0; cp < 32; ++cp) ra += wv[cp] * M2s[c][cp];
            quad += wv[c] * ra;
        }
        float b0   = bfc0[o];
        float mu   = wm + b0;
        float Eh2  = quad + 2.f * b0 * wm + b0 * b0;
        float var  = Eh2 - mu * mu;
        float gr   = gamma[o] * rsqrtf(var + EPSf);
        biasp[o]   = beta[o] + gr * (b0 - mu);
        int ntile = o >> 4, l = o & 15;
#pragma unroll
        for (int kg = 0; kg < 4; ++kg)
#pragma unroll
            for (int j = 0; j < 8; ++j)
                bfragp[ntile * 512 + (l + 16 * kg) * 8 + j] = f2bf(gr * wv[kg * 8 + j]);
    }
}

// ---------------------------------------------------------------------------
// k_fc: fc0' MFMA (folded BN) + ReLU + per-wave LDS transpose + fc1 MFMA +
// masked x update (round-8 verified). 64 px/block, 16 px/wave.
// ---------------------------------------------------------------------------
__global__ __launch_bounds__(256) void k_fc(
    const float* __restrict__ xin,    // [BHW][16]
    const unsigned* __restrict__ dxgu,// [BHW][16 u32]
    const short* __restrict__ bfragp, // [8][64][8]
    const float* __restrict__ biasp,  // [128]
    const short* __restrict__ w1f,    // [4][64][8]
    const float* __restrict__ uS,     // [BHW]
    float* __restrict__ xout)         // [BHW][16]
{
    __shared__ unsigned short hls[4][16][136];

    int tid  = threadIdx.x;
    int lane = tid & 63;
    int w    = __builtin_amdgcn_readfirstlane(tid >> 6);
    int l15  = lane & 15;
    int kg   = lane >> 4;

    int gp0 = blockIdx.x * 64 + w * 16;

    union { uint4 u4; short8 s8; } A;
    A.u4 = *(const uint4*)(dxgu + (size_t)(gp0 + l15) * 16 + kg * 4);

    const short8* bgp = (const short8*)bfragp;
#pragma unroll
    for (int nt = 0; nt < 8; ++nt) {
        float bb = biasp[nt * 16 + l15];
        f32x4 c = {bb, bb, bb, bb};
        c = __builtin_amdgcn_mfma_f32_16x16x32_bf16(A.s8, bgp[nt * 64 + lane], c, 0, 0, 0);
#pragma unroll
        for (int r = 0; r < 4; ++r) {
            float hv = fmaxf(c[r], 0.f);
            hls[w][4 * kg + r][nt * 16 + l15] = (unsigned short)f2bfu(hv);
        }
    }
    __syncthreads();

    const short8* wfp = (const short8*)w1f;
    f32x4 d = {0.f, 0.f, 0.f, 0.f};
#pragma unroll
    for (int ks = 0; ks < 4; ++ks) {
        short8 af = *(const short8*)&hls[w][l15][ks * 32 + kg * 8];
        d = __builtin_amdgcn_mfma_f32_16x16x32_bf16(af, wfp[ks * 64 + lane], d, 0, 0, 0);
    }

#pragma unroll
    for (int r = 0; r < 4; ++r) {
        int gp = gp0 + 4 * kg + r;
        float uu   = uS[gp];
        float xold = xin[(size_t)gp * Cn + l15];
        float add  = (uu > FIREf && l15 != 0) ? d[r] : 0.f;
        xout[(size_t)gp * Cn + l15] = xold + add;
    }
}

// ---------------------------------------------------------------------------
extern "C" void kernel_launch(void* const* d_in, const int* in_sizes, int n_in,
                              void* d_out, int out_size, void* d_ws, size_t ws_size,
                              hipStream_t stream) {
    const float* x0   = (const float*)d_in[0];
    const float* ru   = (const float*)d_in[1];
    const float* wp   = (const float*)d_in[2];
    const float* bp   = (const float*)d_in[3];
    const float* wfc0 = (const float*)d_in[4];
    const float* bfc0 = (const float*)d_in[5];
    const float* wfc1 = (const float*)d_in[6];
    const float* gm   = (const float*)d_in[7];
    const float* bt   = (const float*)d_in[8];
    float*       out  = (float*)d_out;

    float* ws     = (float*)d_ws;
    float* bufA   = ws;                                  // 2,359,296 f
    float* bufB   = bufA + (size_t)BHWn * Cn;            // 2,359,296 f
    float* wtc    = bufB + (size_t)BHWn * Cn;            // 1312 f
    short* w1f    = (short*)(wtc + 1312);                // 2048 s
    short* bfragp = w1f + 2048;                          // 4096 s
    float* biasp  = (float*)(bfragp + 4096);             // 128 f
    float* gsum   = biasp + 128;                         // 10*NCOP*800 f
    unsigned* dxg = (unsigned*)(gsum + STEPSn * NCOP * GSS);  // 2,359,296 u32

    k_prep<<<64, 256, 0, stream>>>(wp, wfc1, wtc, w1f, gsum);

    const float* xcur = x0;
    for (int s = 0; s < STEPSn; ++s) {
        float* gsb = gsum + (size_t)s * NCOP * GSS;
        float* xo = (s == STEPSn - 1) ? out : ((s & 1) ? bufB : bufA);
        k_conv<<<CBLK, 256, 0, stream>>>(xcur, wtc, bp, dxg, gsb);
        k_stats2<<<1, 256, 0, stream>>>(gsb, wfc0, bfc0, gm, bt, bfragp, biasp);
        k_fc<<<BHWn / 64, 256, 0, stream>>>(xcur, dxg, bfragp, biasp, w1f,
                                            ru + (size_t)s * BHWn, xo);
        xcur = xo;
    }
}

// Round 11
// 534.514 us; speedup vs baseline: 1.8801x; 1.0594x over previous
//
#include <hip/hip_runtime.h>

// Problem constants
constexpr int Bn    = 4;
constexpr int Hn    = 192;
constexpr int Wn    = 192;
constexpr int Cn    = 16;
constexpr int HIDn  = 128;
constexpr int HWn   = Hn * Wn;        // 36864
constexpr int BHWn  = Bn * HWn;       // 147456
constexpr int STEPSn = 10;
constexpr int PADn  = 4;
constexpr int KSn   = 9;
constexpr float EPSf  = 1e-5f;
constexpr float FIREf = 0.5f;

// conv kernel geometry: 64 cols x 1 row per block, 4 waves (channel quads)
constexpr int SCOLS = 72;             // 64 + 8 halo
constexpr int TPX   = 64;             // 64 px per block
constexpr int CBLK  = BHWn / TPX;     // 2304 blocks
constexpr int TPI   = HWn / TPX;      // 576 tiles per image
constexpr int GSS   = 800;            // moment floats per copy
constexpr int NCOP  = 32;             // partial copies (contention spread)
constexpr int NXCD  = 8;
constexpr int CPX   = CBLK / NXCD;    // 288 tiles per XCD chunk

typedef __attribute__((ext_vector_type(8))) short short8;
typedef __attribute__((ext_vector_type(4))) float f32x4;

static __device__ __forceinline__ unsigned f2bfu(float f) {
    union { float f; unsigned u; } v; v.f = f;
    return (v.u + 0x7FFFu + ((v.u >> 16) & 1u)) >> 16;   // RNE
}
static __device__ __forceinline__ short f2bf(float f) { return (short)f2bfu(f); }
static __device__ __forceinline__ unsigned pk2(float a, float b) {
    return f2bfu(a) | (f2bfu(b) << 16);
}
static __device__ __forceinline__ float asf(unsigned u) {
    union { unsigned u; float f; } v; v.u = u; return v.f;
}
static __device__ __forceinline__ int refl(int v, int n) {
    v = v < 0 ? -v : v;
    v = v >= n ? 2 * n - 2 - v : v;
    return v;
}

// ---------------------------------------------------------------------------
// Prep (grid-strided, 64 blocks): zero moment partials; block 0 also builds
// wtc[tap][c] and fc1 B-frags (round-5 verified layout).
// ---------------------------------------------------------------------------
__global__ void k_prep(const float* __restrict__ wp,    // [16][81]
                       const float* __restrict__ wfc1,  // [16][128]
                       float* __restrict__ wtc,         // [81][16]
                       short* __restrict__ w1f,         // [4][64][8]
                       float* __restrict__ gsum)        // [10][NCOP][800]
{
    int gid = blockIdx.x * 256 + threadIdx.x;
    for (int i = gid; i < STEPSn * NCOP * GSS; i += gridDim.x * 256) gsum[i] = 0.f;
    if (blockIdx.x == 0) {
        int tid = threadIdx.x;
        for (int i = tid; i < KSn * KSn * Cn; i += 256) {
            int t = i / Cn, c = i - t * Cn;
            wtc[i] = wp[c * (KSn * KSn) + t];
        }
        for (int i = tid; i < 4 * 64 * 8; i += 256) {
            int ks = i >> 9;
            int rem = i & 511;
            int l = rem >> 3, j = rem & 7;
            w1f[i] = f2bf(wfc1[(l & 15) * HIDn + ks * 32 + (l >> 4) * 8 + j]);
        }
    }
}

// ---------------------------------------------------------------------------
// k_cvt: one-time x0 fp32 -> packed bf16 mirror [BHW][8 u32].
// ---------------------------------------------------------------------------
__global__ __launch_bounds__(256) void k_cvt(
    const float* __restrict__ xin, unsigned* __restrict__ xbf)
{
    int gid = blockIdx.x * 256 + threadIdx.x;          // 0 .. BHWn*2-1
    const float4* s = (const float4*)xin + (size_t)gid * 2;
    float4 a = s[0], b = s[1];
    uint4 o = make_uint4(pk2(a.x, a.y), pk2(a.z, a.w),
                         pk2(b.x, b.y), pk2(b.z, b.w));
    ((uint4*)xbf)[gid] = o;
}

// ---------------------------------------------------------------------------
// k_conv (VY=1, scratch-free, batched staging, XCD swizzle):
// bf16 x mirror -> LDS [4][9][72] uint2 -> 81-tap conv (fp32 acc) ->
// dx bf16 [BHW][32] store + dx moments via MFMA (K=64), atomicAdd copy tile&31.
// ---------------------------------------------------------------------------
__global__ __launch_bounds__(256, 6) void k_conv(
    const unsigned* __restrict__ xbf, // [BHW][8 u32] bf16 x mirror
    const float* __restrict__ wtc,    // [81][16]
    const float* __restrict__ bp,     // [16]
    unsigned* __restrict__ dxgu,      // [BHW][16 u32] (32 bf16/px)
    float* __restrict__ gsb)          // [NCOP][800] this step
{
    __shared__ __align__(16) char smraw[4 * KSn * SCOLS * 8];  // 20736 B
    uint2* stg = (uint2*)smraw;                        // [4][9][72] bf16x4
    unsigned* sdx = (unsigned*)smraw;                  // [64][20] u32 (alias)

    int tid  = threadIdx.x;
    int lane = tid & 63;
    int w    = __builtin_amdgcn_readfirstlane(tid >> 6);
    int l15  = lane & 15;
    int kg   = lane >> 4;

    // XCD-aware swizzle: contiguous 288-tile chunk per XCD (2304 % 8 == 0)
    int i    = blockIdx.x;
    int tile = (i & (NXCD - 1)) * CPX + (i >> 3);
    int b    = tile / TPI;
    int t    = tile - b * TPI;
    int y0   = t / 3;                  // output row
    int x0   = (t - y0 * 3) * 64;

    const uint2* xbb = (const uint2*)xbf;   // quad q of px p at [p*4 + q]
    int pbase = b * HWn;

    // ---- stage 9 rows x 72 cols, own quad: issue ALL loads, then write ----
    uint2* stw = stg + w * (KSn * SCOLS);
    uint2 sv[11];
#pragma unroll
    for (int it = 0; it < 11; ++it) {
        int e = it * 64 + lane;
        if (e < KSn * SCOLS) {
            int ri  = e / SCOLS;
            int col = e - ri * SCOLS;
            int yy  = refl(y0 + ri - PADn, Hn);       // inline: no arrays
            int gc  = refl(x0 + col - PADn, Wn);
            sv[it] = xbb[(size_t)(pbase + yy * Wn + gc) * 4 + w];
        }
    }
#pragma unroll
    for (int it = 0; it < 11; ++it) {
        int e = it * 64 + lane;
        if (e < KSn * SCOLS) stw[e] = sv[it];
    }

    // ---- conv: 1 output row, quad w; 81 unconditional taps ----
    const float4* wt4 = (const float4*)wtc;
    float4 a0 = ((const float4*)bp)[w];
    uint2 cen;
#pragma unroll
    for (int ri = 0; ri < KSn; ++ri) {
        uint2 tv[KSn];
#pragma unroll
        for (int dx = 0; dx < KSn; ++dx) tv[dx] = stw[ri * SCOLS + lane + dx];
        if (ri == 4) cen = tv[4];
#pragma unroll
        for (int dx = 0; dx < KSn; ++dx) {
            float c0 = asf(tv[dx].x << 16), c1 = asf(tv[dx].x & 0xffff0000u);
            float c2 = asf(tv[dx].y << 16), c3 = asf(tv[dx].y & 0xffff0000u);
            float4 q = wt4[(ri * KSn + dx) * 4 + w];              // s_load
            a0.x = fmaf(q.x, c0, a0.x); a0.y = fmaf(q.y, c1, a0.y);
            a0.z = fmaf(q.z, c2, a0.z); a0.w = fmaf(q.w, c3, a0.w);
        }
    }
    __syncthreads();   // ALL waves' staging reads done before sdx overwrite

    // ---- dxv -> sdx [64 px][20 u32] (u16 idx = ch 0..31) ----
    {
        unsigned* row = sdx + lane * 20;
        *(uint2*)(row + 2 * w)     = cen;
        *(uint2*)(row + 8 + 2 * w) = make_uint2(pk2(a0.x, a0.y), pk2(a0.z, a0.w));
    }
    __syncthreads();

    // ---- dx global store, coalesced: 4 threads per px, 1 uint4 each ----
    {
        int px = tid >> 2;
        int q  = tid & 3;
        uint4 v = *(const uint4*)(sdx + px * 20 + q * 4);
        int gp  = pbase + y0 * Wn + x0 + px;
        *(uint4*)(dxgu + (size_t)gp * 16 + q * 4) = v;
    }

    // ---- moments via MFMA (round-8 verified mappings; K=64 -> 2 tt) ----
    float* gs = gsb + (size_t)(tile & (NCOP - 1)) * GSS;
    const unsigned short* sdu = (const unsigned short*)smraw;
    if (w == 3) {
        short8 ones;
#pragma unroll
        for (int j = 0; j < 8; ++j) ones[j] = (short)0x3F80;
        f32x4 m0 = {0.f, 0.f, 0.f, 0.f}, m1 = {0.f, 0.f, 0.f, 0.f};
#pragma unroll
        for (int tt = 0; tt < 2; ++tt) {
            short8 fL, fH;
#pragma unroll
            for (int j = 0; j < 8; ++j) {
                int pk = tt * 32 + kg * 8 + j;
                fL[j] = (short)sdu[pk * 40 + l15];
                fH[j] = (short)sdu[pk * 40 + 16 + l15];
            }
            m0 = __builtin_amdgcn_mfma_f32_16x16x32_bf16(fL, ones, m0, 0, 0, 0);
            m1 = __builtin_amdgcn_mfma_f32_16x16x32_bf16(fH, ones, m1, 0, 0, 0);
        }
        if (l15 == 0) {
#pragma unroll
            for (int r = 0; r < 4; ++r) {
                atomicAdd(gs + 768 + 4 * kg + r, m0[r]);
                atomicAdd(gs + 768 + 16 + 4 * kg + r, m1[r]);
            }
        }
    } else {
        int mt = (w == 2) ? 1 : 0;
        int nt = (w == 0) ? 0 : 1;
        f32x4 acc = {0.f, 0.f, 0.f, 0.f};
#pragma unroll
        for (int tt = 0; tt < 2; ++tt) {
            short8 fA, fB;
#pragma unroll
            for (int j = 0; j < 8; ++j) {
                int pk = tt * 32 + kg * 8 + j;
                fA[j] = (short)sdu[pk * 40 + mt * 16 + l15];
                fB[j] = (mt == nt) ? fA[j] : (short)sdu[pk * 40 + nt * 16 + l15];
            }
            acc = __builtin_amdgcn_mfma_f32_16x16x32_bf16(fA, fB, acc, 0, 0, 0);
        }
#pragma unroll
        for (int r = 0; r < 4; ++r)
            atomicAdd(gs + w * 256 + (4 * kg + r) * 16 + l15, acc[r]);
    }
}

// ---------------------------------------------------------------------------
// k_stats2 (1 block): reduce NCOP copies -> moments -> fold BN into fc0
// (round-8 verified math): bfragp = bf16(gr*W0) B-frags, biasp folded.
// ---------------------------------------------------------------------------
__global__ __launch_bounds__(256) void k_stats2(
    const float* __restrict__ gsb,    // [NCOP][800]
    const float* __restrict__ wfc0,   // [128][32]
    const float* __restrict__ bfc0,   // [128]
    const float* __restrict__ gamma,
    const float* __restrict__ beta,
    short* __restrict__ bfragp,       // [8][64][8]
    float* __restrict__ biasp)        // [128]
{
    __shared__ float gsr[GSS];
    __shared__ float M2s[32][32];
    __shared__ float ms[32];
    int tid = threadIdx.x;
    const float inv = 1.0f / BHWn;

    for (int e = tid; e < GSS; e += 256) {
        float acc = 0.f;
#pragma unroll 8
        for (int c2 = 0; c2 < NCOP; ++c2) acc += gsb[c2 * GSS + e];
        gsr[e] = acc;
    }
    __syncthreads();

    for (int i = tid; i < 1024; i += 256) {
        int c = i >> 5, cp = i & 31;
        float v;
        if (c < 16 && cp < 16)       v = gsr[c * 16 + cp];
        else if (c < 16)             v = gsr[256 + c * 16 + (cp - 16)];
        else if (cp >= 16)           v = gsr[512 + (c - 16) * 16 + (cp - 16)];
        else                         v = gsr[256 + cp * 16 + (c - 16)];  // symmetry
        M2s[c][cp] = v * inv;
    }
    if (tid < 32) ms[tid] = gsr[768 + tid] * inv;
    __syncthreads();

    if (tid < HIDn) {
        int o = tid;
        float wv[32];
#pragma unroll
        for (int c = 0; c < 32; ++c) wv[c] = wfc0[o * 32 + c];
        float wm = 0.f;
#pragma unroll
        for (int c = 0; c < 32; ++c) wm += wv[c] * ms[c];
        float quad = 0.f;
#pragma unroll 4
        for (int c = 0; c < 32; ++c) {
            float ra = 0.f;
#pragma unroll
            for (int cp = 0; cp < 32; ++cp) ra += wv[cp] * M2s[c][cp];
            quad += wv[c] * ra;
        }
        float b0   = bfc0[o];
        float mu   = wm + b0;
        float Eh2  = quad + 2.f * b0 * wm + b0 * b0;
        float var  = Eh2 - mu * mu;
        float gr   = gamma[o] * rsqrtf(var + EPSf);
        biasp[o]   = beta[o] + gr * (b0 - mu);
        int ntile = o >> 4, l = o & 15;
#pragma unroll
        for (int kg = 0; kg < 4; ++kg)
#pragma unroll
            for (int j = 0; j < 8; ++j)
                bfragp[ntile * 512 + (l + 16 * kg) * 8 + j] = f2bf(gr * wv[kg * 8 + j]);
    }
}

// ---------------------------------------------------------------------------
// k_fc: fc0' MFMA (folded BN) + ReLU + per-wave LDS transpose + fc1 MFMA +
// masked x update (round-8 verified) + bf16 x mirror write for next k_conv.
// ---------------------------------------------------------------------------
__global__ __launch_bounds__(256) void k_fc(
    const float* __restrict__ xin,    // [BHW][16]
    const unsigned* __restrict__ dxgu,// [BHW][16 u32]
    const short* __restrict__ bfragp, // [8][64][8]
    const float* __restrict__ biasp,  // [128]
    const short* __restrict__ w1f,    // [4][64][8]
    const float* __restrict__ uS,     // [BHW]
    float* __restrict__ xout,         // [BHW][16]
    unsigned* __restrict__ xbf)       // [BHW][8 u32] bf16 mirror of xout
{
    __shared__ unsigned short hls[4][16][136];

    int tid  = threadIdx.x;
    int lane = tid & 63;
    int w    = __builtin_amdgcn_readfirstlane(tid >> 6);
    int l15  = lane & 15;
    int kg   = lane >> 4;

    int gp0 = blockIdx.x * 64 + w * 16;

    union { uint4 u4; short8 s8; } A;
    A.u4 = *(const uint4*)(dxgu + (size_t)(gp0 + l15) * 16 + kg * 4);

    const short8* bgp = (const short8*)bfragp;
#pragma unroll
    for (int nt = 0; nt < 8; ++nt) {
        float bb = biasp[nt * 16 + l15];
        f32x4 c = {bb, bb, bb, bb};
        c = __builtin_amdgcn_mfma_f32_16x16x32_bf16(A.s8, bgp[nt * 64 + lane], c, 0, 0, 0);
#pragma unroll
        for (int r = 0; r < 4; ++r) {
            float hv = fmaxf(c[r], 0.f);
            hls[w][4 * kg + r][nt * 16 + l15] = (unsigned short)f2bfu(hv);
        }
    }
    __syncthreads();

    const short8* wfp = (const short8*)w1f;
    f32x4 d = {0.f, 0.f, 0.f, 0.f};
#pragma unroll
    for (int ks = 0; ks < 4; ++ks) {
        short8 af = *(const short8*)&hls[w][l15][ks * 32 + kg * 8];
        d = __builtin_amdgcn_mfma_f32_16x16x32_bf16(af, wfp[ks * 64 + lane], d, 0, 0, 0);
    }

#pragma unroll
    for (int r = 0; r < 4; ++r) {
        int gp = gp0 + 4 * kg + r;
        float uu   = uS[gp];
        float xold = xin[(size_t)gp * Cn + l15];
        float add  = (uu > FIREf && l15 != 0) ? d[r] : 0.f;
        float xnew = xold + add;
        xout[(size_t)gp * Cn + l15] = xnew;
        float xpair = __shfl_xor(xnew, 1, 64);    // partner channel (l15^1)
        if ((l15 & 1) == 0)
            xbf[(size_t)gp * 8 + (l15 >> 1)] = pk2(xnew, xpair);
    }
}

// ---------------------------------------------------------------------------
extern "C" void kernel_launch(void* const* d_in, const int* in_sizes, int n_in,
                              void* d_out, int out_size, void* d_ws, size_t ws_size,
                              hipStream_t stream) {
    const float* x0   = (const float*)d_in[0];
    const float* ru   = (const float*)d_in[1];
    const float* wp   = (const float*)d_in[2];
    const float* bp   = (const float*)d_in[3];
    const float* wfc0 = (const float*)d_in[4];
    const float* bfc0 = (const float*)d_in[5];
    const float* wfc1 = (const float*)d_in[6];
    const float* gm   = (const float*)d_in[7];
    const float* bt   = (const float*)d_in[8];
    float*       out  = (float*)d_out;

    float* ws     = (float*)d_ws;
    float* bufA   = ws;                                  // 2,359,296 f
    float* bufB   = bufA + (size_t)BHWn * Cn;            // 2,359,296 f
    float* wtc    = bufB + (size_t)BHWn * Cn;            // 1312 f
    short* w1f    = (short*)(wtc + 1312);                // 2048 s
    short* bfragp = w1f + 2048;                          // 4096 s
    float* biasp  = (float*)(bfragp + 4096);             // 128 f
    float* gsum   = biasp + 128;                         // 10*NCOP*800 f
    unsigned* dxg = (unsigned*)(gsum + STEPSn * NCOP * GSS);  // 2,359,296 u32
    unsigned* xbf = dxg + (size_t)BHWn * 16;             // 1,179,648 u32

    k_prep<<<64, 256, 0, stream>>>(wp, wfc1, wtc, w1f, gsum);
    k_cvt<<<BHWn * 2 / 256, 256, 0, stream>>>(x0, xbf);

    const float* xcur = x0;
    for (int s = 0; s < STEPSn; ++s) {
        float* gsb = gsum + (size_t)s * NCOP * GSS;
        float* xo = (s == STEPSn - 1) ? out : ((s & 1) ? bufB : bufA);
        k_conv<<<CBLK, 256, 0, stream>>>(xbf, wtc, bp, dxg, gsb);
        k_stats2<<<1, 256, 0, stream>>>(gsb, wfc0, bfc0, gm, bt, bfragp, biasp);
        k_fc<<<BHWn / 64, 256, 0, stream>>>(xcur, dxg, bfragp, biasp, w1f,
                                            ru + (size_t)s * BHWn, xo, xbf);
        xcur = xo;
    }
}

// Round 12
// 497.704 us; speedup vs baseline: 2.0191x; 1.0740x over previous
//
#include <hip/hip_runtime.h>
#include <hip/hip_fp16.h>

// Problem constants
constexpr int Bn    = 4;
constexpr int Hn    = 192;
constexpr int Wn    = 192;
constexpr int Cn    = 16;
constexpr int HIDn  = 128;
constexpr int HWn   = Hn * Wn;        // 36864
constexpr int BHWn  = Bn * HWn;       // 147456
constexpr int STEPSn = 10;
constexpr int PADn  = 4;
constexpr int KSn   = 9;
constexpr float EPSf  = 1e-5f;
constexpr float FIREf = 0.5f;

// conv kernel geometry: 64 cols x 1 row per block, 4 waves (channel quads)
constexpr int SCOLS = 72;             // 64 + 8 halo
constexpr int TPX   = 64;             // 64 px per block
constexpr int CBLK  = BHWn / TPX;     // 2304 blocks
constexpr int TPI   = HWn / TPX;      // 576 tiles per image
constexpr int GSS   = 800;            // moment floats per copy
constexpr int NCOP  = 32;             // partial copies (contention spread)
constexpr int NXCD  = 8;
constexpr int CPX   = CBLK / NXCD;    // 288 tiles per XCD chunk

typedef __attribute__((ext_vector_type(8))) short short8;
typedef __attribute__((ext_vector_type(4))) float f32x4;

static __device__ __forceinline__ short f2hs(float f) {
    __half h = __float2half(f);
    return (short)__half_as_ushort(h);
}
static __device__ __forceinline__ unsigned pkh2(float a, float b) {
    __half2 h = __floats2half2_rn(a, b);
    union { __half2 h; unsigned u; } v; v.h = h; return v.u;
}
static __device__ __forceinline__ __half2 ash2(unsigned u) {
    union { unsigned u; __half2 h; } v; v.u = u; return v.h;
}
static __device__ __forceinline__ unsigned ash2u(__half2 h) {
    union { __half2 h; unsigned u; } v; v.h = h; return v.u;
}
static __device__ __forceinline__ int refl(int v, int n) {
    v = v < 0 ? -v : v;
    v = v >= n ? 2 * n - 2 - v : v;
    return v;
}

// ---------------------------------------------------------------------------
// Prep (grid-strided, 64 blocks): zero moment partials; block 0 also builds
// wtch (half2-packed conv weights [81][4] uint2-of-pairs) and fc1 f16 B-frags.
// ---------------------------------------------------------------------------
__global__ void k_prep(const float* __restrict__ wp,    // [16][81]
                       const float* __restrict__ wfc1,  // [16][128]
                       unsigned* __restrict__ wtch,     // [81][8] u32 (c pairs)
                       short* __restrict__ w1f,         // [4][64][8] f16
                       float* __restrict__ gsum)        // [10][NCOP][800]
{
    int gid = blockIdx.x * 256 + threadIdx.x;
    for (int i = gid; i < STEPSn * NCOP * GSS; i += gridDim.x * 256) gsum[i] = 0.f;
    if (blockIdx.x == 0) {
        int tid = threadIdx.x;
        for (int i = tid; i < KSn * KSn * 8; i += 256) {
            int t = i >> 3, pr = i & 7;
            wtch[i] = pkh2(wp[(pr * 2) * 81 + t], wp[(pr * 2 + 1) * 81 + t]);
        }
        for (int i = tid; i < 4 * 64 * 8; i += 256) {
            int ks = i >> 9;
            int rem = i & 511;
            int l = rem >> 3, j = rem & 7;
            w1f[i] = f2hs(wfc1[(l & 15) * HIDn + ks * 32 + (l >> 4) * 8 + j]);
        }
    }
}

// ---------------------------------------------------------------------------
// k_cvt: one-time x0 fp32 -> packed fp16 mirror [BHW][8 u32].
// ---------------------------------------------------------------------------
__global__ __launch_bounds__(256) void k_cvt(
    const float* __restrict__ xin, unsigned* __restrict__ xhf)
{
    int gid = blockIdx.x * 256 + threadIdx.x;          // 0 .. BHWn*2-1
    const float4* s = (const float4*)xin + (size_t)gid * 2;
    float4 a = s[0], b = s[1];
    uint4 o = make_uint4(pkh2(a.x, a.y), pkh2(a.z, a.w),
                         pkh2(b.x, b.y), pkh2(b.z, b.w));
    ((uint4*)xhf)[gid] = o;
}

// ---------------------------------------------------------------------------
// k_conv (fp16): fp16 x mirror -> LDS [4][9][72] uint2 -> 81-tap conv via
// __hfma2 (2 VALU/tap, packed fp16 acc) -> dx f16 [BHW][32] store +
// dx moments via f16 MFMA (K=64), atomicAdd into copy tile&31.
// ---------------------------------------------------------------------------
__global__ __launch_bounds__(256, 6) void k_conv(
    const unsigned* __restrict__ xhf, // [BHW][8 u32] fp16 x mirror
    const unsigned* __restrict__ wtch,// [81][8] u32 (half2 pairs)
    const float* __restrict__ bp,     // [16]
    unsigned* __restrict__ dxgu,      // [BHW][16 u32] (32 f16/px)
    float* __restrict__ gsb)          // [NCOP][800] this step
{
    __shared__ __align__(16) char smraw[4 * KSn * SCOLS * 8];  // 20736 B
    uint2* stg = (uint2*)smraw;                        // [4][9][72] f16x4
    unsigned* sdx = (unsigned*)smraw;                  // [64][20] u32 (alias)

    int tid  = threadIdx.x;
    int lane = tid & 63;
    int w    = __builtin_amdgcn_readfirstlane(tid >> 6);
    int l15  = lane & 15;
    int kg   = lane >> 4;

    // XCD-aware swizzle: contiguous 288-tile chunk per XCD
    int i    = blockIdx.x;
    int tile = (i & (NXCD - 1)) * CPX + (i >> 3);
    int b    = tile / TPI;
    int t    = tile - b * TPI;
    int y0   = t / 3;
    int x0   = (t - y0 * 3) * 64;

    const uint2* xbb = (const uint2*)xhf;   // quad q of px p at [p*4 + q]
    int pbase = b * HWn;

    // ---- stage 9 rows x 72 cols, own quad: issue ALL loads, then write ----
    uint2* stw = stg + w * (KSn * SCOLS);
    uint2 sv[11];
#pragma unroll
    for (int it = 0; it < 11; ++it) {
        int e = it * 64 + lane;
        if (e < KSn * SCOLS) {
            int ri  = e / SCOLS;
            int col = e - ri * SCOLS;
            int yy  = refl(y0 + ri - PADn, Hn);
            int gc  = refl(x0 + col - PADn, Wn);
            sv[it] = xbb[(size_t)(pbase + yy * Wn + gc) * 4 + w];
        }
    }
#pragma unroll
    for (int it = 0; it < 11; ++it) {
        int e = it * 64 + lane;
        if (e < KSn * SCOLS) stw[e] = sv[it];
    }

    // ---- conv: 1 output row, quad w; 81 taps x 2 __hfma2 each ----
    const uint2* wt2 = (const uint2*)wtch;             // [81][4] uint2
    __half2 a01 = __floats2half2_rn(bp[4 * w + 0], bp[4 * w + 1]);
    __half2 a23 = __floats2half2_rn(bp[4 * w + 2], bp[4 * w + 3]);
    uint2 cen;
#pragma unroll
    for (int ri = 0; ri < KSn; ++ri) {
        uint2 tv[KSn];
#pragma unroll
        for (int dx = 0; dx < KSn; ++dx) tv[dx] = stw[ri * SCOLS + lane + dx];
        if (ri == 4) cen = tv[4];
#pragma unroll
        for (int dx = 0; dx < KSn; ++dx) {
            uint2 wq = wt2[(ri * KSn + dx) * 4 + w];              // s_load
            a01 = __hfma2(ash2(wq.x), ash2(tv[dx].x), a01);
            a23 = __hfma2(ash2(wq.y), ash2(tv[dx].y), a23);
        }
    }
    __syncthreads();   // ALL waves' staging reads done before sdx overwrite

    // ---- dxv -> sdx [64 px][20 u32] (u16 idx = ch 0..31, f16) ----
    {
        unsigned* row = sdx + lane * 20;
        *(uint2*)(row + 2 * w)     = cen;
        *(uint2*)(row + 8 + 2 * w) = make_uint2(ash2u(a01), ash2u(a23));
    }
    __syncthreads();

    // ---- dx global store, coalesced: 4 threads per px, 1 uint4 each ----
    {
        int px = tid >> 2;
        int q  = tid & 3;
        uint4 v = *(const uint4*)(sdx + px * 20 + q * 4);
        int gp  = pbase + y0 * Wn + x0 + px;
        *(uint4*)(dxgu + (size_t)gp * 16 + q * 4) = v;
    }

    // ---- moments via f16 MFMA (verified mappings; K=64 -> 2 tt) ----
    float* gs = gsb + (size_t)(tile & (NCOP - 1)) * GSS;
    const unsigned short* sdu = (const unsigned short*)smraw;
    if (w == 3) {
        short8 ones;
#pragma unroll
        for (int j = 0; j < 8; ++j) ones[j] = (short)0x3C00;     // f16 1.0
        f32x4 m0 = {0.f, 0.f, 0.f, 0.f}, m1 = {0.f, 0.f, 0.f, 0.f};
#pragma unroll
        for (int tt = 0; tt < 2; ++tt) {
            short8 fL, fH;
#pragma unroll
            for (int j = 0; j < 8; ++j) {
                int pk = tt * 32 + kg * 8 + j;
                fL[j] = (short)sdu[pk * 40 + l15];
                fH[j] = (short)sdu[pk * 40 + 16 + l15];
            }
            m0 = __builtin_amdgcn_mfma_f32_16x16x32_f16(fL, ones, m0, 0, 0, 0);
            m1 = __builtin_amdgcn_mfma_f32_16x16x32_f16(fH, ones, m1, 0, 0, 0);
        }
        if (l15 == 0) {
#pragma unroll
            for (int r = 0; r < 4; ++r) {
                atomicAdd(gs + 768 + 4 * kg + r, m0[r]);
                atomicAdd(gs + 768 + 16 + 4 * kg + r, m1[r]);
            }
        }
    } else {
        int mt = (w == 2) ? 1 : 0;
        int nt = (w == 0) ? 0 : 1;
        f32x4 acc = {0.f, 0.f, 0.f, 0.f};
#pragma unroll
        for (int tt = 0; tt < 2; ++tt) {
            short8 fA, fB;
#pragma unroll
            for (int j = 0; j < 8; ++j) {
                int pk = tt * 32 + kg * 8 + j;
                fA[j] = (short)sdu[pk * 40 + mt * 16 + l15];
                fB[j] = (mt == nt) ? fA[j] : (short)sdu[pk * 40 + nt * 16 + l15];
            }
            acc = __builtin_amdgcn_mfma_f32_16x16x32_f16(fA, fB, acc, 0, 0, 0);
        }
#pragma unroll
        for (int r = 0; r < 4; ++r)
            atomicAdd(gs + w * 256 + (4 * kg + r) * 16 + l15, acc[r]);
    }
}

// ---------------------------------------------------------------------------
// k_stats2 (1 block): reduce NCOP copies -> moments -> fold BN into fc0:
// bfragp = f16(gr*W0) B-frags, biasp folded (verified math).
// ---------------------------------------------------------------------------
__global__ __launch_bounds__(256) void k_stats2(
    const float* __restrict__ gsb,    // [NCOP][800]
    const float* __restrict__ wfc0,   // [128][32]
    const float* __restrict__ bfc0,   // [128]
    const float* __restrict__ gamma,
    const float* __restrict__ beta,
    short* __restrict__ bfragp,       // [8][64][8] f16
    float* __restrict__ biasp)        // [128]
{
    __shared__ float gsr[GSS];
    __shared__ float M2s[32][32];
    __shared__ float ms[32];
    int tid = threadIdx.x;
    const float inv = 1.0f / BHWn;

    for (int e = tid; e < GSS; e += 256) {
        float acc = 0.f;
#pragma unroll 8
        for (int c2 = 0; c2 < NCOP; ++c2) acc += gsb[c2 * GSS + e];
        gsr[e] = acc;
    }
    __syncthreads();

    for (int i = tid; i < 1024; i += 256) {
        int c = i >> 5, cp = i & 31;
        float v;
        if (c < 16 && cp < 16)       v = gsr[c * 16 + cp];
        else if (c < 16)             v = gsr[256 + c * 16 + (cp - 16)];
        else if (cp >= 16)           v = gsr[512 + (c - 16) * 16 + (cp - 16)];
        else                         v = gsr[256 + cp * 16 + (c - 16)];  // symmetry
        M2s[c][cp] = v * inv;
    }
    if (tid < 32) ms[tid] = gsr[768 + tid] * inv;
    __syncthreads();

    if (tid < HIDn) {
        int o = tid;
        float wv[32];
#pragma unroll
        for (int c = 0; c < 32; ++c) wv[c] = wfc0[o * 32 + c];
        float wm = 0.f;
#pragma unroll
        for (int c = 0; c < 32; ++c) wm += wv[c] * ms[c];
        float quad = 0.f;
#pragma unroll 4
        for (int c = 0; c < 32; ++c) {
            float ra = 0.f;
#pragma unroll
            for (int cp = 0; cp < 32; ++cp) ra += wv[cp] * M2s[c][cp];
            quad += wv[c] * ra;
        }
        float b0   = bfc0[o];
        float mu   = wm + b0;
        float Eh2  = quad + 2.f * b0 * wm + b0 * b0;
        float var  = Eh2 - mu * mu;
        float gr   = gamma[o] * rsqrtf(var + EPSf);
        biasp[o]   = beta[o] + gr * (b0 - mu);
        int ntile = o >> 4, l = o & 15;
#pragma unroll
        for (int kg = 0; kg < 4; ++kg)
#pragma unroll
            for (int j = 0; j < 8; ++j)
                bfragp[ntile * 512 + (l + 16 * kg) * 8 + j] = f2hs(gr * wv[kg * 8 + j]);
    }
}

// ---------------------------------------------------------------------------
// k_fc: fc0' f16 MFMA (folded BN) + ReLU + per-wave LDS transpose + fc1 f16
// MFMA + masked x update + fp16 x mirror write for next k_conv.
// ---------------------------------------------------------------------------
__global__ __launch_bounds__(256) void k_fc(
    const float* __restrict__ xin,    // [BHW][16]
    const unsigned* __restrict__ dxgu,// [BHW][16 u32] f16
    const short* __restrict__ bfragp, // [8][64][8] f16
    const float* __restrict__ biasp,  // [128]
    const short* __restrict__ w1f,    // [4][64][8] f16
    const float* __restrict__ uS,     // [BHW]
    float* __restrict__ xout,         // [BHW][16]
    unsigned* __restrict__ xhf)       // [BHW][8 u32] fp16 mirror of xout
{
    __shared__ unsigned short hls[4][16][136];

    int tid  = threadIdx.x;
    int lane = tid & 63;
    int w    = __builtin_amdgcn_readfirstlane(tid >> 6);
    int l15  = lane & 15;
    int kg   = lane >> 4;

    int gp0 = blockIdx.x * 64 + w * 16;

    union { uint4 u4; short8 s8; } A;
    A.u4 = *(const uint4*)(dxgu + (size_t)(gp0 + l15) * 16 + kg * 4);

    const short8* bgp = (const short8*)bfragp;
#pragma unroll
    for (int nt = 0; nt < 8; ++nt) {
        float bb = biasp[nt * 16 + l15];
        f32x4 c = {bb, bb, bb, bb};
        c = __builtin_amdgcn_mfma_f32_16x16x32_f16(A.s8, bgp[nt * 64 + lane], c, 0, 0, 0);
#pragma unroll
        for (int r = 0; r < 4; ++r) {
            float hv = fmaxf(c[r], 0.f);
            hls[w][4 * kg + r][nt * 16 + l15] = __half_as_ushort(__float2half(hv));
        }
    }
    __syncthreads();

    const short8* wfp = (const short8*)w1f;
    f32x4 d = {0.f, 0.f, 0.f, 0.f};
#pragma unroll
    for (int ks = 0; ks < 4; ++ks) {
        short8 af = *(const short8*)&hls[w][l15][ks * 32 + kg * 8];
        d = __builtin_amdgcn_mfma_f32_16x16x32_f16(af, wfp[ks * 64 + lane], d, 0, 0, 0);
    }

#pragma unroll
    for (int r = 0; r < 4; ++r) {
        int gp = gp0 + 4 * kg + r;
        float uu   = uS[gp];
        float xold = xin[(size_t)gp * Cn + l15];
        float add  = (uu > FIREf && l15 != 0) ? d[r] : 0.f;
        float xnew = xold + add;
        xout[(size_t)gp * Cn + l15] = xnew;
        float xpair = __shfl_xor(xnew, 1, 64);    // partner channel (l15^1)
        if ((l15 & 1) == 0)
            xhf[(size_t)gp * 8 + (l15 >> 1)] = pkh2(xnew, xpair);
    }
}

// ---------------------------------------------------------------------------
extern "C" void kernel_launch(void* const* d_in, const int* in_sizes, int n_in,
                              void* d_out, int out_size, void* d_ws, size_t ws_size,
                              hipStream_t stream) {
    const float* x0   = (const float*)d_in[0];
    const float* ru   = (const float*)d_in[1];
    const float* wp   = (const float*)d_in[2];
    const float* bp   = (const float*)d_in[3];
    const float* wfc0 = (const float*)d_in[4];
    const float* bfc0 = (const float*)d_in[5];
    const float* wfc1 = (const float*)d_in[6];
    const float* gm   = (const float*)d_in[7];
    const float* bt   = (const float*)d_in[8];
    float*       out  = (float*)d_out;

    float* ws      = (float*)d_ws;
    float* bufA    = ws;                                 // 2,359,296 f
    float* bufB    = bufA + (size_t)BHWn * Cn;           // 2,359,296 f
    unsigned* wtch = (unsigned*)(bufB + (size_t)BHWn * Cn);  // 648 -> pad 656 u32
    short* w1f     = (short*)(wtch + 656);               // 2048 s
    short* bfragp  = w1f + 2048;                         // 4096 s
    float* biasp   = (float*)(bfragp + 4096);            // 128 f
    float* gsum    = biasp + 128;                        // 10*NCOP*800 f
    unsigned* dxg  = (unsigned*)(gsum + STEPSn * NCOP * GSS);  // 2,359,296 u32
    unsigned* xhf  = dxg + (size_t)BHWn * 16;            // 1,179,648 u32

    k_prep<<<64, 256, 0, stream>>>(wp, wfc1, wtch, w1f, gsum);
    k_cvt<<<BHWn * 2 / 256, 256, 0, stream>>>(x0, xhf);

    const float* xcur = x0;
    for (int s = 0; s < STEPSn; ++s) {
        float* gsb = gsum + (size_t)s * NCOP * GSS;
        float* xo = (s == STEPSn - 1) ? out : ((s & 1) ? bufB : bufA);
        k_conv<<<CBLK, 256, 0, stream>>>(xhf, wtch, bp, dxg, gsb);
        k_stats2<<<1, 256, 0, stream>>>(gsb, wfc0, bfc0, gm, bt, bfragp, biasp);
        k_fc<<<BHWn / 64, 256, 0, stream>>>(xcur, dxg, bfragp, biasp, w1f,
                                            ru + (size_t)s * BHWn, xo, xhf);
        xcur = xo;
    }
}